// Round 1
// baseline (277.859 us; speedup 1.0000x reference)
//
#include <hip/hip_runtime.h>
#include <hip/hip_bf16.h>

#define S 1024
#define D 64
#define BH 64
#define NEG (-1000000000.0f)
#define SCALE 0.125f

typedef __attribute__((ext_vector_type(8))) short short8;
typedef __attribute__((ext_vector_type(16))) float f32x16;

// fp32 -> bf16 round-to-nearest-even (inputs are finite, skip NaN path)
static __device__ __forceinline__ short f2bf(float f) {
    union { float f; unsigned u; } v; v.f = f;
    unsigned r = (v.u + 0x7fffu + ((v.u >> 16) & 1u)) >> 16;
    return (short)r;
}

// load 8 consecutive fp32 from 16B-aligned p, convert to bf16 MFMA half-frag
static __device__ __forceinline__ short8 load_frag8(const float* p) {
    float4 a = *(const float4*)p;
    float4 b = *(const float4*)(p + 4);
    short8 r;
    r[0] = f2bf(a.x); r[1] = f2bf(a.y); r[2] = f2bf(a.z); r[3] = f2bf(a.w);
    r[4] = f2bf(b.x); r[5] = f2bf(b.y); r[6] = f2bf(b.z); r[7] = f2bf(b.w);
    return r;
}

// Phase 1: rcp_colsum[bh, kcol] = 1 / sum_q exp(masked(q.k/8))
// Block: 256 thr (4 waves). Each block owns 32 k-columns of one (b,h); each
// wave covers disjoint 32-row q-tiles (8 iterations -> all 1024 q).
__global__ __launch_bounds__(256) void colsum_kernel(
    const float* __restrict__ q, const float* __restrict__ k,
    const int* __restrict__ mask, float* __restrict__ rcp) {
  int tid = threadIdx.x;
  int wave = tid >> 6, lane = tid & 63;
  int l31 = lane & 31, hi = lane >> 5;
  int kb = blockIdx.x * 32;
  int bh = blockIdx.y;
  const float* qh = q + (size_t)bh * S * D;
  const float* kh = k + (size_t)bh * S * D;
  const int* mh = mask + (size_t)bh * S * S;

  // B operand: k rows kb + l31, k-dim split (l>>5)*8
  short8 bfrag[4];
  const float* kp = kh + (size_t)(kb + l31) * D + hi * 8;
#pragma unroll
  for (int s = 0; s < 4; ++s) bfrag[s] = load_frag8(kp + s * 16);

  int kcol = kb + l31;
  float colpart = 0.f;
  for (int it = 0; it < 8; ++it) {
    int q0 = it * 128 + wave * 32;
    const float* qp = qh + (size_t)(q0 + l31) * D + hi * 8;
    short8 afrag[4];
#pragma unroll
    for (int s = 0; s < 4; ++s) afrag[s] = load_frag8(qp + s * 16);
    f32x16 acc = {};
#pragma unroll
    for (int s = 0; s < 4; ++s)
      acc = __builtin_amdgcn_mfma_f32_32x32x16_bf16(afrag[s], bfrag[s], acc, 0, 0, 0);
#pragma unroll
    for (int r = 0; r < 16; ++r) {
      int qrow = q0 + (r & 3) + 8 * (r >> 2) + 4 * hi;
      int m = mh[(size_t)qrow * S + kcol];
      float sc = m ? acc[r] * SCALE : NEG;
      colpart += __expf(sc);   // exp(-1e9) underflows to exactly 0
    }
  }
  // lanes l and l+32 hold the same column (rows differ by 4*hi)
  colpart += __shfl_xor(colpart, 32, 64);
  __shared__ float red[4][32];
  if (lane < 32) red[wave][lane] = colpart;
  __syncthreads();
  if (tid < 32) {
    float t = red[0][tid] + red[1][tid] + red[2][tid] + red[3][tid];
    rcp[(size_t)bh * S + kb + tid] = 1.0f / t;
  }
}

// Phase 2: recompute scores, normalize, write attn, and out = attn @ v.
// Block: 256 thr (4 waves), each wave owns 32 q-rows; loop over 32 k-tiles.
__global__ __launch_bounds__(256) void attn_out_kernel(
    const float* __restrict__ q, const float* __restrict__ k,
    const float* __restrict__ v, const int* __restrict__ mask,
    const float* __restrict__ rcp, float* __restrict__ outp,
    float* __restrict__ attnp) {
  int tid = threadIdx.x;
  int wave = tid >> 6, lane = tid & 63;
  int l31 = lane & 31, hi = lane >> 5;
  int bh = blockIdx.y;
  int qb = blockIdx.x * 128 + wave * 32;
  const float* qh = q + (size_t)bh * S * D;
  const float* kh = k + (size_t)bh * S * D;
  const float* vh = v + (size_t)bh * S * D;
  const int* mh = mask + (size_t)bh * S * S;
  const float* rch = rcp + (size_t)bh * S;
  float* ah = attnp + (size_t)bh * S * S;

  __shared__ float sm[4][32][33];  // per-wave attn tile, +1 pad (bank-conflict-free)

  // A operand (held all kernel): q rows qb + l31
  short8 afrag[4];
  const float* qp = qh + (size_t)(qb + l31) * D + hi * 8;
#pragma unroll
  for (int s = 0; s < 4; ++s) afrag[s] = load_frag8(qp + s * 16);

  f32x16 oacc0 = {}, oacc1 = {};

  for (int kt = 0; kt < 32; ++kt) {
    int kb2 = kt * 32;
    const float* kp = kh + (size_t)(kb2 + l31) * D + hi * 8;
    short8 bfrag[4];
#pragma unroll
    for (int s = 0; s < 4; ++s) bfrag[s] = load_frag8(kp + s * 16);
    f32x16 acc = {};
#pragma unroll
    for (int s = 0; s < 4; ++s)
      acc = __builtin_amdgcn_mfma_f32_32x32x16_bf16(afrag[s], bfrag[s], acc, 0, 0, 0);

    int kcol = kb2 + l31;
    float rc = rch[kcol];
#pragma unroll
    for (int r = 0; r < 16; ++r) {
      int ql = (r & 3) + 8 * (r >> 2) + 4 * hi;
      int qrow = qb + ql;
      int m = mh[(size_t)qrow * S + kcol];
      float e = __expf(m ? acc[r] * SCALE : NEG) * rc;
      ah[(size_t)qrow * S + kcol] = e;   // coalesced: 128B runs per half-wave
      sm[wave][ql][l31] = e;             // padded row -> conflict-free
    }

    // PV: out[q][d] += attn[q][kk] * v[kk][d], kk split in two 16-subtiles
#pragma unroll
    for (int s2 = 0; s2 < 2; ++s2) {
      short8 pa;
      const float* smrow = &sm[wave][l31][0];
#pragma unroll
      for (int e = 0; e < 8; ++e)
        pa[e] = f2bf(smrow[s2 * 16 + hi * 8 + e]);
      const float* vp = vh + (size_t)(kb2 + s2 * 16 + hi * 8) * D + l31;
      short8 vf0, vf1;
#pragma unroll
      for (int e = 0; e < 8; ++e) {
        vf0[e] = f2bf(vp[(size_t)e * D]);
        vf1[e] = f2bf(vp[(size_t)e * D + 32]);
      }
      oacc0 = __builtin_amdgcn_mfma_f32_32x32x16_bf16(pa, vf0, oacc0, 0, 0, 0);
      oacc1 = __builtin_amdgcn_mfma_f32_32x32x16_bf16(pa, vf1, oacc1, 0, 0, 0);
    }
  }

  float* oh = outp + (size_t)bh * S * D;
#pragma unroll
  for (int r = 0; r < 16; ++r) {
    int ql = (r & 3) + 8 * (r >> 2) + 4 * hi;
    oh[(size_t)(qb + ql) * D + l31] = oacc0[r];
    oh[(size_t)(qb + ql) * D + 32 + l31] = oacc1[r];
  }
}

extern "C" void kernel_launch(void* const* d_in, const int* in_sizes, int n_in,
                              void* d_out, int out_size, void* d_ws, size_t ws_size,
                              hipStream_t stream) {
  const float* q = (const float*)d_in[0];
  const float* k = (const float*)d_in[1];
  const float* v = (const float*)d_in[2];
  const int* mask = (const int*)d_in[3];
  float* outp = (float*)d_out;
  float* attnp = outp + (size_t)BH * S * D;   // out first, then attn
  float* rcp = (float*)d_ws;                  // B*H*S floats = 256 KB

  colsum_kernel<<<dim3(S / 32, BH), 256, 0, stream>>>(q, k, mask, rcp);
  attn_out_kernel<<<dim3(S / 128, BH), 256, 0, stream>>>(q, k, v, mask, rcp, outp, attnp);
}